// Round 7
// baseline (349.585 us; speedup 1.0000x reference)
//
#include <hip/hip_runtime.h>
#include <cstdint>

#define NPOINTS 524288
#define NLEV 24
#define CAP 262144
#define HASHMUL 2531011u
#define PTS_PER_BLOCK 512
#define BLOCKS_PER_LEVEL (NPOINTS / PTS_PER_BLOCK)   // 1024

#define NBUCKET 262144            // 6 bits per dim, 18-bit Morton
#define WS_MAIN_B  ((size_t)NLEV * NPOINTS * 8)      // 100,663,296
#define ORIG_B     ((size_t)NPOINTS * 4)             //   2,097,152
#define PS_B       ((size_t)NPOINTS * 12)            //   6,291,456
#define HIST_B     ((size_t)NBUCKET * 4)             //   1,048,576

typedef float v2f __attribute__((ext_vector_type(2)));

// ---------------- sorting helpers ----------------

__device__ __forceinline__ uint32_t expand_bits(uint32_t v) {
    v = (v | (v << 16)) & 0x030000FFu;
    v = (v | (v << 8))  & 0x0300F00Fu;
    v = (v | (v << 4))  & 0x030C30C3u;
    v = (v | (v << 2))  & 0x09249249u;
    return v;
}

__device__ __forceinline__ uint32_t morton_code(float x, float y, float z) {
    int xi = (int)(x * 64.0f); xi = xi < 0 ? 0 : (xi > 63 ? 63 : xi);
    int yi = (int)(y * 64.0f); yi = yi < 0 ? 0 : (yi > 63 ? 63 : yi);
    int zi = (int)(z * 64.0f); zi = zi < 0 ? 0 : (zi > 63 ? 63 : zi);
    return expand_bits((uint32_t)xi) | (expand_bits((uint32_t)yi) << 1)
         | (expand_bits((uint32_t)zi) << 2);
}

__global__ __launch_bounds__(256) void zero_kernel(int* __restrict__ p, int n) {
    int i = blockIdx.x * 256 + threadIdx.x;
    if (i < n) p[i] = 0;
}

__global__ __launch_bounds__(256) void hist_kernel(
    const float* __restrict__ pos, int* __restrict__ hist) {
    int n = blockIdx.x * 256 + threadIdx.x;
    float x = pos[n*3+0], y = pos[n*3+1], z = pos[n*3+2];
    atomicAdd(&hist[morton_code(x, y, z)], 1);
}

// one-block exclusive scan of NBUCKET counts -> offs
__global__ __launch_bounds__(256) void scan_kernel(
    const int* __restrict__ hist, int* __restrict__ offs) {
    __shared__ int sums[256];
    const int t = threadIdx.x;
    const int CHUNK = NBUCKET / 256;    // 1024
    const int base = t * CHUNK;
    int s = 0;
    #pragma unroll 8
    for (int i = 0; i < CHUNK; ++i) s += hist[base + i];
    sums[t] = s;
    __syncthreads();
    // Hillis-Steele inclusive scan over sums[256]
    for (int d = 1; d < 256; d <<= 1) {
        int v = (t >= d) ? sums[t - d] : 0;
        __syncthreads();
        sums[t] += v;
        __syncthreads();
    }
    int run = sums[t] - s;              // exclusive prefix of this chunk
    for (int i = 0; i < CHUNK; ++i) { offs[base + i] = run; run += hist[base + i]; }
}

__global__ __launch_bounds__(256) void scatter_kernel(
    const float* __restrict__ pos, int* __restrict__ offs,
    float* __restrict__ pos_sorted, int* __restrict__ orig) {
    int n = blockIdx.x * 256 + threadIdx.x;
    float x = pos[n*3+0], y = pos[n*3+1], z = pos[n*3+2];
    uint32_t code = morton_code(x, y, z);
    int slot = atomicAdd(&offs[code], 1);
    pos_sorted[slot*3+0] = x;
    pos_sorted[slot*3+1] = y;
    pos_sorted[slot*3+2] = z;
    orig[slot] = n;
}

// ---------------- permuto core ----------------

// Per-point simplex setup: outputs 4 table indices + 4 barycentric weights.
// Bit-exact op ordering vs the JAX reference (see round-0 notes).
__device__ __forceinline__ void prep_point(
    const float p0, const float p1, const float p2,
    const float sf0, const float sf1, const float sf2,
    const float sh0, const float sh1, const float sh2,
    uint32_t* __restrict__ ix, float* __restrict__ w)
{
    const float cf0 = (p0 + sh0) * sf0;
    const float cf1 = (p1 + sh1) * sf1;
    const float cf2 = (p2 + sh2) * sf2;

    const float S2 = cf2;
    const float S1 = cf2 + cf1;
    const float S0 = S1 + cf0;

    float E[4];
    E[0] = S0;
    E[1] = S1 - 1.0f*cf0;
    E[2] = S2 - 2.0f*cf1;
    E[3] = 0.0f - 3.0f*cf2;

    float rem0[4];
    float sumrem = 0.0f;
    #pragma unroll
    for (int i = 0; i < 4; ++i) {
        float v  = E[i] * 0.25f;
        float up = ceilf(v)  * 4.0f;
        float dn = floorf(v) * 4.0f;
        rem0[i] = (up - E[i] < E[i] - dn) ? up : dn;
        sumrem += rem0[i];
    }
    const int sum_val = (int)rintf(sumrem * 0.25f);

    float diff[4];
    #pragma unroll
    for (int i = 0; i < 4; ++i) diff[i] = E[i] - rem0[i];

    int rank[4];
    #pragma unroll
    for (int i = 0; i < 4; ++i) {
        int rk = 0;
        #pragma unroll
        for (int j = 0; j < 4; ++j) {
            if (j > i)      rk += (diff[j] >  diff[i]) ? 1 : 0;
            else if (j < i) rk += (diff[j] >= diff[i]) ? 1 : 0;
        }
        rk += sum_val;
        if (rk < 0)      { rk += 4; rem0[i] += 4.0f; }
        else if (rk > 3) { rk -= 4; rem0[i] -= 4.0f; }
        rank[i] = rk;
    }

    float delta[4];
    #pragma unroll
    for (int i = 0; i < 4; ++i) delta[i] = (E[i] - rem0[i]) * 0.25f;

    float b[5];
    #pragma unroll
    for (int k = 0; k < 5; ++k) {
        float acc = 0.0f;
        #pragma unroll
        for (int i = 0; i < 4; ++i) {
            int ti = 3 - rank[i];
            float m = ((ti == k) ? 1.0f : 0.0f) - ((ti == (k-1)) ? 1.0f : 0.0f);
            acc += delta[i] * m;
        }
        b[k] = acc;
    }
    b[0] += 1.0f + b[4];

    int rem0i[4];
    #pragma unroll
    for (int i = 0; i < 4; ++i) rem0i[i] = (int)rintf(rem0[i]);

    #pragma unroll
    for (int r = 0; r < 4; ++r) {
        uint32_t h = 0u;
        #pragma unroll
        for (int i = 0; i < 3; ++i) {
            int key = rem0i[i] + r - 4 * ((rank[i] > 3 - r) ? 1 : 0);
            h = (h + (uint32_t)key) * HASHMUL;
        }
        ix[r] = h & (uint32_t)(CAP - 1);
        w[r]  = b[r];
    }
}

// One block = (one level, 512 consecutive points), 2 points per thread.
// blockIdx swizzled so XCD x handles levels {x, x+8, x+16} sequentially.
template <bool USE_WS>
__global__ __launch_bounds__(256, 6) void permuto_kernel(
    const float* __restrict__ pos,      // [N,3] (sorted or original order)
    const float* __restrict__ lattice,  // [L,C,2]
    const float* __restrict__ shift,    // [L,3]
    const float* __restrict__ anneal,   // [L]
    const float* __restrict__ scale,    // [L]
    v2f* __restrict__ ws,               // [L][N] float2 (level-major)
    float* __restrict__ out)            // [N, L*2] (direct fallback)
{
    __shared__ float s_pos[PTS_PER_BLOCK * 3];   // 6 KB

    const int t    = threadIdx.x;
    const int bid  = blockIdx.x;
    const int xcd  = bid & 7;
    const int slot = bid >> 3;                   // 0..3071
    const int l    = xcd + 8 * (slot >> 10);     // level
    const int nb   = slot & (BLOCKS_PER_LEVEL - 1);
    const int pbase = nb * PTS_PER_BLOCK;        // first point of block

    // coalesced position staging: 1536 floats, 6 per thread
    {
        const float* src = pos + (size_t)pbase * 3;
        #pragma unroll
        for (int k = 0; k < 6; ++k)
            s_pos[k * 256 + t] = src[k * 256 + t];
    }

    // block-uniform level constants (scalar)
    const float sc  = scale[l];
    const float sf0 = sc / sqrtf(2.0f);
    const float sf1 = sc / sqrtf(6.0f);
    const float sf2 = sc / sqrtf(12.0f);
    const float sh0 = shift[l*3+0];
    const float sh1 = shift[l*3+1];
    const float sh2 = shift[l*3+2];
    const float an  = anneal[l];

    __syncthreads();

    // point A = local t, point B = local t+256
    const float a0 = s_pos[3*t+0], a1 = s_pos[3*t+1], a2 = s_pos[3*t+2];
    const float b0 = s_pos[3*(t+256)+0], b1 = s_pos[3*(t+256)+1], b2 = s_pos[3*(t+256)+2];

    uint32_t ixA[4], ixB[4];
    float    wA[4],  wB[4];
    prep_point(a0, a1, a2, sf0, sf1, sf2, sh0, sh1, sh2, ixA, wA);
    prep_point(b0, b1, b2, sf0, sf1, sf2, sh0, sh1, sh2, ixB, wB);

    const v2f* __restrict__ tbl =
        reinterpret_cast<const v2f*>(lattice) + (size_t)l * CAP;

    // issue all 8 gathers back-to-back (sorted order -> TA merges same-line lanes)
    v2f vA[4], vB[4];
    #pragma unroll
    for (int r = 0; r < 4; ++r) vA[r] = tbl[ixA[r]];
    #pragma unroll
    for (int r = 0; r < 4; ++r) vB[r] = tbl[ixB[r]];

    float oA0 = 0.f, oA1 = 0.f, oB0 = 0.f, oB1 = 0.f;
    #pragma unroll
    for (int r = 0; r < 4; ++r) {
        oA0 += wA[r] * vA[r].x;  oA1 += wA[r] * vA[r].y;
        oB0 += wB[r] * vB[r].x;  oB1 += wB[r] * vB[r].y;
    }

    v2f resA, resB;
    resA.x = oA0 * an;  resA.y = oA1 * an;
    resB.x = oB0 * an;  resB.y = oB1 * an;

    if (USE_WS) {
        // nontemporal streaming stores (don't evict the table from L2)
        v2f* pA = ws + (size_t)l * NPOINTS + pbase + t;
        v2f* pB = pA + 256;
        __builtin_nontemporal_store(resA, pA);
        __builtin_nontemporal_store(resB, pB);
    } else {
        *reinterpret_cast<v2f*>(out + (size_t)(pbase + t) * (NLEV*2) + l*2) = resA;
        *reinterpret_cast<v2f*>(out + (size_t)(pbase + 256 + t) * (NLEV*2) + l*2) = resB;
    }
}

// Transpose [L][N] float2 -> [N][48] float, optional row indirection.
template <bool IND>
__global__ __launch_bounds__(256) void transpose_kernel(
    const float* __restrict__ ws,
    const int* __restrict__ orig,
    float* __restrict__ out)
{
    __shared__ float lds[128 * 49];
    __shared__ int s_orig[128];
    const int t  = threadIdx.x;
    const int n0 = blockIdx.x * 128;

    if (IND && t < 128) s_orig[t] = orig[n0 + t];

    #pragma unroll
    for (int l = 0; l < NLEV; ++l) {
        const float v = ws[(size_t)l * (NPOINTS*2) + (size_t)n0 * 2 + t];
        const int p = t >> 1;
        const int f = t & 1;
        lds[p * 49 + l * 2 + f] = v;
    }
    __syncthreads();

    if (IND) {
        #pragma unroll
        for (int it = 0; it < 24; ++it) {
            const int flat = it * 256 + t;
            const int p = flat / 48;
            const int c = flat - p * 48;
            out[(size_t)s_orig[p] * 48 + c] = lds[p * 49 + c];
        }
    } else {
        const size_t obase = (size_t)n0 * 48;
        #pragma unroll
        for (int it = 0; it < 24; ++it) {
            const int flat = it * 256 + t;
            const int p = flat / 48;
            const int c = flat - p * 48;
            out[obase + flat] = lds[p * 49 + c];
        }
    }
}

extern "C" void kernel_launch(void* const* d_in, const int* in_sizes, int n_in,
                              void* d_out, int out_size, void* d_ws, size_t ws_size,
                              hipStream_t stream) {
    const float* pos     = (const float*)d_in[0];
    const float* lattice = (const float*)d_in[1];
    const float* shift   = (const float*)d_in[2];
    const float* anneal  = (const float*)d_in[3];
    const float* scale   = (const float*)d_in[4];
    float* out = (float*)d_out;

    const int grid = NLEV * BLOCKS_PER_LEVEL;    // 24576

    uint8_t* w8 = (uint8_t*)d_ws;
    v2f*   ws_main    = (v2f*)w8;
    int*   orig       = (int*)(w8 + WS_MAIN_B);
    float* pos_sorted = (float*)(w8 + WS_MAIN_B + ORIG_B);
    int*   hist       = (int*)(w8 + WS_MAIN_B + ORIG_B + PS_B);
    int*   offs       = (int*)(w8 + WS_MAIN_B + ORIG_B + PS_B + HIST_B);
    const size_t ws_sorted_need = WS_MAIN_B + ORIG_B + PS_B + 2 * HIST_B;

    if (ws_size >= ws_sorted_need) {
        // spatial bucket-sort of points (Morton 6 bits/dim)
        zero_kernel<<<NBUCKET / 256, 256, 0, stream>>>(hist, NBUCKET);
        hist_kernel<<<NPOINTS / 256, 256, 0, stream>>>(pos, hist);
        scan_kernel<<<1, 256, 0, stream>>>(hist, offs);
        scatter_kernel<<<NPOINTS / 256, 256, 0, stream>>>(pos, offs, pos_sorted, orig);
        permuto_kernel<true><<<grid, 256, 0, stream>>>(
            pos_sorted, lattice, shift, anneal, scale, ws_main, out);
        transpose_kernel<true><<<NPOINTS / 128, 256, 0, stream>>>(
            (const float*)ws_main, orig, out);
    } else if (ws_size >= WS_MAIN_B) {
        permuto_kernel<true><<<grid, 256, 0, stream>>>(
            pos, lattice, shift, anneal, scale, ws_main, out);
        transpose_kernel<false><<<NPOINTS / 128, 256, 0, stream>>>(
            (const float*)ws_main, nullptr, out);
    } else {
        permuto_kernel<false><<<grid, 256, 0, stream>>>(
            pos, lattice, shift, anneal, scale, nullptr, out);
    }
}

// Round 8
// 271.131 us; speedup vs baseline: 1.2894x; 1.2894x over previous
//
#include <hip/hip_runtime.h>
#include <cstdint>

#define NPOINTS 524288
#define NLEV 24
#define CAP 262144
#define HASHMUL 2531011u
#define PTS_PER_BLOCK 512
#define BLOCKS_PER_LEVEL (NPOINTS / PTS_PER_BLOCK)   // 1024

#define NBUCKET 32768             // 5 bits per dim, 15-bit Morton
#define WS_H_B   ((size_t)NLEV * NPOINTS * 4)        // 50,331,648 (half2 per (l,n))
#define POS4_B   ((size_t)NPOINTS * 16)              //  8,388,608
#define HIST_B   ((size_t)NBUCKET * 4)               //    131,072

typedef float v2f  __attribute__((ext_vector_type(2)));
typedef float v4f  __attribute__((ext_vector_type(4)));
typedef _Float16 f16x2 __attribute__((ext_vector_type(2)));

// ---------------- sorting helpers ----------------

__device__ __forceinline__ uint32_t expand_bits(uint32_t v) {
    v = (v | (v << 16)) & 0x030000FFu;
    v = (v | (v << 8))  & 0x0300F00Fu;
    v = (v | (v << 4))  & 0x030C30C3u;
    v = (v | (v << 2))  & 0x09249249u;
    return v;
}

__device__ __forceinline__ uint32_t morton5(float x, float y, float z) {
    int xi = (int)(x * 32.0f); xi = xi < 0 ? 0 : (xi > 31 ? 31 : xi);
    int yi = (int)(y * 32.0f); yi = yi < 0 ? 0 : (yi > 31 ? 31 : yi);
    int zi = (int)(z * 32.0f); zi = zi < 0 ? 0 : (zi > 31 ? 31 : zi);
    return expand_bits((uint32_t)xi) | (expand_bits((uint32_t)yi) << 1)
         | (expand_bits((uint32_t)zi) << 2);
}

__global__ __launch_bounds__(256) void hist_kernel(
    const float* __restrict__ pos, int* __restrict__ hist) {
    int n = blockIdx.x * 256 + threadIdx.x;
    float x = pos[n*3+0], y = pos[n*3+1], z = pos[n*3+2];
    atomicAdd(&hist[morton5(x, y, z)], 1);
}

// single-block exclusive scan of NBUCKET counts -> offs (256 KB total traffic)
__global__ __launch_bounds__(256) void scan_kernel(
    const int* __restrict__ hist, int* __restrict__ offs) {
    __shared__ int sums[256];
    const int t = threadIdx.x;
    const int CHUNK = NBUCKET / 256;    // 128
    const int4* h4 = reinterpret_cast<const int4*>(hist) + t * (CHUNK/4);
    int s = 0;
    #pragma unroll
    for (int i = 0; i < CHUNK/4; ++i) { int4 v = h4[i]; s += v.x + v.y + v.z + v.w; }
    sums[t] = s;
    __syncthreads();
    for (int d = 1; d < 256; d <<= 1) {
        int v = (t >= d) ? sums[t - d] : 0;
        __syncthreads();
        sums[t] += v;
        __syncthreads();
    }
    int run = sums[t] - s;              // exclusive prefix of this chunk
    int4* o4 = reinterpret_cast<int4*>(offs) + t * (CHUNK/4);
    #pragma unroll
    for (int i = 0; i < CHUNK/4; ++i) {
        int4 v = h4[i]; int4 o;
        o.x = run; run += v.x;
        o.y = run; run += v.y;
        o.z = run; run += v.z;
        o.w = run; run += v.w;
        o4[i] = o;
    }
}

// scatter: pos4[slot] = {x, y, z, bitcast(orig_index)}
__global__ __launch_bounds__(256) void scatter_kernel(
    const float* __restrict__ pos, int* __restrict__ offs,
    v4f* __restrict__ pos4) {
    int n = blockIdx.x * 256 + threadIdx.x;
    float x = pos[n*3+0], y = pos[n*3+1], z = pos[n*3+2];
    uint32_t code = morton5(x, y, z);
    int slot = atomicAdd(&offs[code], 1);
    v4f v; v.x = x; v.y = y; v.z = z; v.w = __uint_as_float((uint32_t)n);
    pos4[slot] = v;
}

// ---------------- permuto core ----------------

__device__ __forceinline__ void prep_point(
    const float p0, const float p1, const float p2,
    const float sf0, const float sf1, const float sf2,
    const float sh0, const float sh1, const float sh2,
    uint32_t* __restrict__ ix, float* __restrict__ w)
{
    const float cf0 = (p0 + sh0) * sf0;
    const float cf1 = (p1 + sh1) * sf1;
    const float cf2 = (p2 + sh2) * sf2;

    const float S2 = cf2;
    const float S1 = cf2 + cf1;
    const float S0 = S1 + cf0;

    float E[4];
    E[0] = S0;
    E[1] = S1 - 1.0f*cf0;
    E[2] = S2 - 2.0f*cf1;
    E[3] = 0.0f - 3.0f*cf2;

    float rem0[4];
    float sumrem = 0.0f;
    #pragma unroll
    for (int i = 0; i < 4; ++i) {
        float v  = E[i] * 0.25f;
        float up = ceilf(v)  * 4.0f;
        float dn = floorf(v) * 4.0f;
        rem0[i] = (up - E[i] < E[i] - dn) ? up : dn;
        sumrem += rem0[i];
    }
    const int sum_val = (int)rintf(sumrem * 0.25f);

    float diff[4];
    #pragma unroll
    for (int i = 0; i < 4; ++i) diff[i] = E[i] - rem0[i];

    int rank[4];
    #pragma unroll
    for (int i = 0; i < 4; ++i) {
        int rk = 0;
        #pragma unroll
        for (int j = 0; j < 4; ++j) {
            if (j > i)      rk += (diff[j] >  diff[i]) ? 1 : 0;
            else if (j < i) rk += (diff[j] >= diff[i]) ? 1 : 0;
        }
        rk += sum_val;
        if (rk < 0)      { rk += 4; rem0[i] += 4.0f; }
        else if (rk > 3) { rk -= 4; rem0[i] -= 4.0f; }
        rank[i] = rk;
    }

    float delta[4];
    #pragma unroll
    for (int i = 0; i < 4; ++i) delta[i] = (E[i] - rem0[i]) * 0.25f;

    float b[5];
    #pragma unroll
    for (int k = 0; k < 5; ++k) {
        float acc = 0.0f;
        #pragma unroll
        for (int i = 0; i < 4; ++i) {
            int ti = 3 - rank[i];
            float m = ((ti == k) ? 1.0f : 0.0f) - ((ti == (k-1)) ? 1.0f : 0.0f);
            acc += delta[i] * m;
        }
        b[k] = acc;
    }
    b[0] += 1.0f + b[4];

    int rem0i[4];
    #pragma unroll
    for (int i = 0; i < 4; ++i) rem0i[i] = (int)rintf(rem0[i]);

    #pragma unroll
    for (int r = 0; r < 4; ++r) {
        uint32_t h = 0u;
        #pragma unroll
        for (int i = 0; i < 3; ++i) {
            int key = rem0i[i] + r - 4 * ((rank[i] > 3 - r) ? 1 : 0);
            h = (h + (uint32_t)key) * HASHMUL;
        }
        ix[r] = h & (uint32_t)(CAP - 1);
        w[r]  = b[r];
    }
}

__device__ __forceinline__ uint32_t pack_h2_scaled(float x, float y) {
    f16x2 ph;
    ph.x = (_Float16)(x * 256.0f);   // *2^8 exact; keeps values in f16 normal range
    ph.y = (_Float16)(y * 256.0f);
    return __builtin_bit_cast(uint32_t, ph);
}

// One block = (one level, 512 sorted points), 2 points per thread.
// blockIdx swizzled so XCD x handles levels {x, x+8, x+16} sequentially.
__global__ __launch_bounds__(256, 6) void permuto_kernel(
    const v4f* __restrict__ pos4,       // [N] {x,y,z,orig} sorted
    const float* __restrict__ lattice,  // [L,C,2]
    const float* __restrict__ shift,    // [L,3]
    const float* __restrict__ anneal,   // [L]
    const float* __restrict__ scale,    // [L]
    uint32_t* __restrict__ ws_u)        // [L][N] half2 (scaled by 256)
{
    __shared__ v4f s_pos[PTS_PER_BLOCK];   // 8 KB

    const int t    = threadIdx.x;
    const int bid  = blockIdx.x;
    const int xcd  = bid & 7;
    const int slot = bid >> 3;
    const int l    = xcd + 8 * (slot >> 10);
    const int nb   = slot & (BLOCKS_PER_LEVEL - 1);
    const int pbase = nb * PTS_PER_BLOCK;

    {
        const v4f* src = pos4 + pbase;
        s_pos[t]       = src[t];
        s_pos[t + 256] = src[t + 256];
    }

    const float sc  = scale[l];
    const float sf0 = sc / sqrtf(2.0f);
    const float sf1 = sc / sqrtf(6.0f);
    const float sf2 = sc / sqrtf(12.0f);
    const float sh0 = shift[l*3+0];
    const float sh1 = shift[l*3+1];
    const float sh2 = shift[l*3+2];
    const float an  = anneal[l];

    __syncthreads();

    const v4f pA = s_pos[t];
    const v4f pB = s_pos[t + 256];

    uint32_t ixA[4], ixB[4];
    float    wA[4],  wB[4];
    prep_point(pA.x, pA.y, pA.z, sf0, sf1, sf2, sh0, sh1, sh2, ixA, wA);
    prep_point(pB.x, pB.y, pB.z, sf0, sf1, sf2, sh0, sh1, sh2, ixB, wB);

    const v2f* __restrict__ tbl =
        reinterpret_cast<const v2f*>(lattice) + (size_t)l * CAP;

    v2f vA[4], vB[4];
    #pragma unroll
    for (int r = 0; r < 4; ++r) vA[r] = tbl[ixA[r]];
    #pragma unroll
    for (int r = 0; r < 4; ++r) vB[r] = tbl[ixB[r]];

    float oA0 = 0.f, oA1 = 0.f, oB0 = 0.f, oB1 = 0.f;
    #pragma unroll
    for (int r = 0; r < 4; ++r) {
        oA0 += wA[r] * vA[r].x;  oA1 += wA[r] * vA[r].y;
        oB0 += wB[r] * vB[r].x;  oB1 += wB[r] * vB[r].y;
    }

    const uint32_t uA = pack_h2_scaled(oA0 * an, oA1 * an);
    const uint32_t uB = pack_h2_scaled(oB0 * an, oB1 * an);

    uint32_t* pWA = ws_u + (size_t)l * NPOINTS + pbase + t;
    __builtin_nontemporal_store(uA, pWA);
    __builtin_nontemporal_store(uB, pWA + 256);
}

// LDS-free transpose: 4 lanes per point; lane m holds output cols 12m..12m+11.
// Loads: per wave-instr, 4 levels x 16 consecutive points = 4 full 64B lines.
// Stores: 3 x float4 per lane into line-aligned 192B rows at out[orig*48].
__global__ __launch_bounds__(256) void transpose_kernel(
    const uint32_t* __restrict__ ws_u,   // [L][N] half2 scaled
    const uint32_t* __restrict__ pos4u,  // pos4 as uints (w = orig index)
    float* __restrict__ out)             // [N][48]
{
    const int t  = threadIdx.x;
    const int m  = t & 3;
    const int p  = blockIdx.x * 64 + (t >> 2);

    const uint32_t orig = pos4u[4*p + 3];

    float r[12];
    #pragma unroll
    for (int i = 0; i < 6; ++i) {
        const int l = m * 6 + i;
        const uint32_t u = ws_u[(size_t)l * NPOINTS + p];
        const f16x2 hh = __builtin_bit_cast(f16x2, u);
        r[2*i+0] = (float)hh.x * 0.00390625f;   // /256 exact
        r[2*i+1] = (float)hh.y * 0.00390625f;
    }

    float* orow = out + (size_t)orig * 48 + m * 12;
    #pragma unroll
    for (int j = 0; j < 3; ++j) {
        v4f v; v.x = r[4*j]; v.y = r[4*j+1]; v.z = r[4*j+2]; v.w = r[4*j+3];
        *reinterpret_cast<v4f*>(orow + 4*j) = v;
    }
}

// Fallback (ws too small): unsorted, direct scattered out writes.
__global__ __launch_bounds__(256) void permuto_direct(
    const float* __restrict__ pos,
    const float* __restrict__ lattice,
    const float* __restrict__ shift,
    const float* __restrict__ anneal,
    const float* __restrict__ scale,
    float* __restrict__ out)
{
    const int tid = blockIdx.x * 256 + threadIdx.x;
    const int n = tid / NLEV;
    const int l = tid - n * NLEV;

    const float sc  = scale[l];
    const float sf0 = sc / sqrtf(2.0f);
    const float sf1 = sc / sqrtf(6.0f);
    const float sf2 = sc / sqrtf(12.0f);

    uint32_t ix[4]; float w[4];
    prep_point(pos[n*3+0], pos[n*3+1], pos[n*3+2],
               sf0, sf1, sf2, shift[l*3+0], shift[l*3+1], shift[l*3+2], ix, w);

    const v2f* tbl = reinterpret_cast<const v2f*>(lattice) + (size_t)l * CAP;
    float o0 = 0.f, o1 = 0.f;
    #pragma unroll
    for (int r = 0; r < 4; ++r) {
        v2f v = tbl[ix[r]];
        o0 += w[r] * v.x;  o1 += w[r] * v.y;
    }
    const float an = anneal[l];
    v2f res; res.x = o0 * an; res.y = o1 * an;
    *reinterpret_cast<v2f*>(out + (size_t)n * (NLEV*2) + l*2) = res;
}

extern "C" void kernel_launch(void* const* d_in, const int* in_sizes, int n_in,
                              void* d_out, int out_size, void* d_ws, size_t ws_size,
                              hipStream_t stream) {
    const float* pos     = (const float*)d_in[0];
    const float* lattice = (const float*)d_in[1];
    const float* shift   = (const float*)d_in[2];
    const float* anneal  = (const float*)d_in[3];
    const float* scale   = (const float*)d_in[4];
    float* out = (float*)d_out;

    uint8_t* w8 = (uint8_t*)d_ws;
    uint32_t* ws_u = (uint32_t*)w8;
    v4f*      pos4 = (v4f*)(w8 + WS_H_B);
    int*      hist = (int*)(w8 + WS_H_B + POS4_B);
    int*      offs = (int*)(w8 + WS_H_B + POS4_B + HIST_B);
    const size_t need = WS_H_B + POS4_B + 2 * HIST_B;

    if (ws_size >= need) {
        hipMemsetAsync(hist, 0, HIST_B, stream);
        hist_kernel<<<NPOINTS / 256, 256, 0, stream>>>(pos, hist);
        scan_kernel<<<1, 256, 0, stream>>>(hist, offs);
        scatter_kernel<<<NPOINTS / 256, 256, 0, stream>>>(pos, offs, pos4);
        permuto_kernel<<<NLEV * BLOCKS_PER_LEVEL, 256, 0, stream>>>(
            pos4, lattice, shift, anneal, scale, ws_u);
        transpose_kernel<<<NPOINTS / 64, 256, 0, stream>>>(
            ws_u, (const uint32_t*)pos4, out);
    } else {
        permuto_direct<<<(NPOINTS * NLEV) / 256, 256, 0, stream>>>(
            pos, lattice, shift, anneal, scale, out);
    }
}

// Round 9
// 238.951 us; speedup vs baseline: 1.4630x; 1.1347x over previous
//
#include <hip/hip_runtime.h>
#include <cstdint>

#define NPOINTS 524288
#define NLEV 24
#define CAP 262144
#define HASHMUL 2531011u
#define PTS_PER_BLOCK 512
#define BLOCKS_PER_LEVEL (NPOINTS / PTS_PER_BLOCK)   // 1024

#define NBUCKET 4096              // 4 bits per dim, 12-bit Morton
#define SORT_BLOCKS 64
#define SORT_PTS (NPOINTS / SORT_BLOCKS)             // 8192 points per sort block

#define WS_H_B   ((size_t)NLEV * NPOINTS * 4)        // 50,331,648 (half2 per (l,n))
#define POS4_B   ((size_t)NPOINTS * 16)              //  8,388,608
#define PART_B   ((size_t)SORT_BLOCKS * NBUCKET * 4) //  1,048,576
#define BASE_B   PART_B
#define TOT_B    ((size_t)NBUCKET * 4)               //     16,384

typedef float v2f  __attribute__((ext_vector_type(2)));
typedef float v4f  __attribute__((ext_vector_type(4)));
typedef _Float16 f16x2 __attribute__((ext_vector_type(2)));

// ---------------- sorting (no global atomics) ----------------

__device__ __forceinline__ uint32_t expand_bits(uint32_t v) {
    v = (v | (v << 16)) & 0x030000FFu;
    v = (v | (v << 8))  & 0x0300F00Fu;
    v = (v | (v << 4))  & 0x030C30C3u;
    v = (v | (v << 2))  & 0x09249249u;
    return v;
}

__device__ __forceinline__ uint32_t morton4(float x, float y, float z) {
    int xi = (int)(x * 16.0f); xi = xi < 0 ? 0 : (xi > 15 ? 15 : xi);
    int yi = (int)(y * 16.0f); yi = yi < 0 ? 0 : (yi > 15 ? 15 : yi);
    int zi = (int)(z * 16.0f); zi = zi < 0 ? 0 : (zi > 15 ? 15 : zi);
    return expand_bits((uint32_t)xi) | (expand_bits((uint32_t)yi) << 1)
         | (expand_bits((uint32_t)zi) << 2);
}

// per-block LDS histogram -> part[b][j]  (no global atomics)
__global__ __launch_bounds__(256) void hist_kernel(
    const float* __restrict__ pos, int* __restrict__ part) {
    __shared__ int h[NBUCKET];
    const int t = threadIdx.x, b = blockIdx.x;
    #pragma unroll
    for (int i = t; i < NBUCKET; i += 256) h[i] = 0;
    __syncthreads();
    const int n0 = b * SORT_PTS;
    for (int i = 0; i < SORT_PTS / 256; ++i) {
        const int n = n0 + i * 256 + t;
        atomicAdd(&h[morton4(pos[n*3], pos[n*3+1], pos[n*3+2])], 1);
    }
    __syncthreads();
    #pragma unroll
    for (int i = t; i < NBUCKET; i += 256) part[b * NBUCKET + i] = h[i];
}

// tot[j] = sum_b part[b][j]
__global__ __launch_bounds__(256) void scanA_kernel(
    const int* __restrict__ part, int* __restrict__ tot) {
    const int j = blockIdx.x * 256 + threadIdx.x;
    int s = 0;
    #pragma unroll 8
    for (int b = 0; b < SORT_BLOCKS; ++b) s += part[b * NBUCKET + j];
    tot[j] = s;
}

// single-block exclusive scan of tot[NBUCKET] -> G
__global__ __launch_bounds__(256) void scanB_kernel(
    const int* __restrict__ tot, int* __restrict__ G) {
    __shared__ int sums[256];
    const int t = threadIdx.x;
    const int CH = NBUCKET / 256;   // 16
    int loc[CH];
    int s = 0;
    #pragma unroll
    for (int k = 0; k < CH; ++k) { loc[k] = tot[t * CH + k]; s += loc[k]; }
    sums[t] = s;
    __syncthreads();
    for (int d = 1; d < 256; d <<= 1) {
        int v = (t >= d) ? sums[t - d] : 0;
        __syncthreads();
        sums[t] += v;
        __syncthreads();
    }
    int run = sums[t] - s;
    #pragma unroll
    for (int k = 0; k < CH; ++k) { G[t * CH + k] = run; run += loc[k]; }
}

// base[b][j] = G[j] + sum_{b'<b} part[b'][j]
__global__ __launch_bounds__(256) void scanC_kernel(
    const int* __restrict__ part, const int* __restrict__ G,
    int* __restrict__ base) {
    const int j = blockIdx.x * 256 + threadIdx.x;
    int run = G[j];
    #pragma unroll 8
    for (int b = 0; b < SORT_BLOCKS; ++b) {
        base[b * NBUCKET + j] = run;
        run += part[b * NBUCKET + j];
    }
}

// scatter via LDS counters seeded with per-block bases (no global atomics)
__global__ __launch_bounds__(256) void scatter_kernel(
    const float* __restrict__ pos, const int* __restrict__ base,
    v4f* __restrict__ pos4) {
    __shared__ int cnt[NBUCKET];
    const int t = threadIdx.x, b = blockIdx.x;
    #pragma unroll
    for (int i = t; i < NBUCKET; i += 256) cnt[i] = base[b * NBUCKET + i];
    __syncthreads();
    const int n0 = b * SORT_PTS;
    for (int i = 0; i < SORT_PTS / 256; ++i) {
        const int n = n0 + i * 256 + t;
        const float x = pos[n*3], y = pos[n*3+1], z = pos[n*3+2];
        const int slot = atomicAdd(&cnt[morton4(x, y, z)], 1);
        v4f v; v.x = x; v.y = y; v.z = z; v.w = __uint_as_float((uint32_t)n);
        pos4[slot] = v;
    }
}

// ---------------- permuto core ----------------

__device__ __forceinline__ void prep_point(
    const float p0, const float p1, const float p2,
    const float sf0, const float sf1, const float sf2,
    const float sh0, const float sh1, const float sh2,
    uint32_t* __restrict__ ix, float* __restrict__ w)
{
    const float cf0 = (p0 + sh0) * sf0;
    const float cf1 = (p1 + sh1) * sf1;
    const float cf2 = (p2 + sh2) * sf2;

    const float S2 = cf2;
    const float S1 = cf2 + cf1;
    const float S0 = S1 + cf0;

    float E[4];
    E[0] = S0;
    E[1] = S1 - 1.0f*cf0;
    E[2] = S2 - 2.0f*cf1;
    E[3] = 0.0f - 3.0f*cf2;

    float rem0[4];
    float sumrem = 0.0f;
    #pragma unroll
    for (int i = 0; i < 4; ++i) {
        float v  = E[i] * 0.25f;
        float up = ceilf(v)  * 4.0f;
        float dn = floorf(v) * 4.0f;
        rem0[i] = (up - E[i] < E[i] - dn) ? up : dn;
        sumrem += rem0[i];
    }
    const int sum_val = (int)rintf(sumrem * 0.25f);

    float diff[4];
    #pragma unroll
    for (int i = 0; i < 4; ++i) diff[i] = E[i] - rem0[i];

    int rank[4];
    #pragma unroll
    for (int i = 0; i < 4; ++i) {
        int rk = 0;
        #pragma unroll
        for (int j = 0; j < 4; ++j) {
            if (j > i)      rk += (diff[j] >  diff[i]) ? 1 : 0;
            else if (j < i) rk += (diff[j] >= diff[i]) ? 1 : 0;
        }
        rk += sum_val;
        if (rk < 0)      { rk += 4; rem0[i] += 4.0f; }
        else if (rk > 3) { rk -= 4; rem0[i] -= 4.0f; }
        rank[i] = rk;
    }

    float delta[4];
    #pragma unroll
    for (int i = 0; i < 4; ++i) delta[i] = (E[i] - rem0[i]) * 0.25f;

    float b[5];
    #pragma unroll
    for (int k = 0; k < 5; ++k) {
        float acc = 0.0f;
        #pragma unroll
        for (int i = 0; i < 4; ++i) {
            int ti = 3 - rank[i];
            float m = ((ti == k) ? 1.0f : 0.0f) - ((ti == (k-1)) ? 1.0f : 0.0f);
            acc += delta[i] * m;
        }
        b[k] = acc;
    }
    b[0] += 1.0f + b[4];

    int rem0i[4];
    #pragma unroll
    for (int i = 0; i < 4; ++i) rem0i[i] = (int)rintf(rem0[i]);

    #pragma unroll
    for (int r = 0; r < 4; ++r) {
        uint32_t h = 0u;
        #pragma unroll
        for (int i = 0; i < 3; ++i) {
            int key = rem0i[i] + r - 4 * ((rank[i] > 3 - r) ? 1 : 0);
            h = (h + (uint32_t)key) * HASHMUL;
        }
        ix[r] = h & (uint32_t)(CAP - 1);
        w[r]  = b[r];
    }
}

__device__ __forceinline__ uint32_t pack_h2_scaled(float x, float y) {
    f16x2 ph;
    ph.x = (_Float16)(x * 256.0f);   // *2^8 exact; keeps values in f16 normal range
    ph.y = (_Float16)(y * 256.0f);
    return __builtin_bit_cast(uint32_t, ph);
}

// One block = (one level, 512 sorted points), 2 points per thread.
// blockIdx swizzled so XCD x handles levels {x, x+8, x+16} sequentially.
__global__ __launch_bounds__(256, 6) void permuto_kernel(
    const v4f* __restrict__ pos4,       // [N] {x,y,z,orig} sorted
    const float* __restrict__ lattice,  // [L,C,2]
    const float* __restrict__ shift,    // [L,3]
    const float* __restrict__ anneal,   // [L]
    const float* __restrict__ scale,    // [L]
    uint32_t* __restrict__ ws_u)        // [L][N] half2 (scaled by 256)
{
    __shared__ v4f s_pos[PTS_PER_BLOCK];   // 8 KB

    const int t    = threadIdx.x;
    const int bid  = blockIdx.x;
    const int xcd  = bid & 7;
    const int slot = bid >> 3;
    const int l    = xcd + 8 * (slot >> 10);
    const int nb   = slot & (BLOCKS_PER_LEVEL - 1);
    const int pbase = nb * PTS_PER_BLOCK;

    {
        const v4f* src = pos4 + pbase;
        s_pos[t]       = src[t];
        s_pos[t + 256] = src[t + 256];
    }

    const float sc  = scale[l];
    const float sf0 = sc / sqrtf(2.0f);
    const float sf1 = sc / sqrtf(6.0f);
    const float sf2 = sc / sqrtf(12.0f);
    const float sh0 = shift[l*3+0];
    const float sh1 = shift[l*3+1];
    const float sh2 = shift[l*3+2];
    const float an  = anneal[l];

    __syncthreads();

    const v4f pA = s_pos[t];
    const v4f pB = s_pos[t + 256];

    uint32_t ixA[4], ixB[4];
    float    wA[4],  wB[4];
    prep_point(pA.x, pA.y, pA.z, sf0, sf1, sf2, sh0, sh1, sh2, ixA, wA);
    prep_point(pB.x, pB.y, pB.z, sf0, sf1, sf2, sh0, sh1, sh2, ixB, wB);

    const v2f* __restrict__ tbl =
        reinterpret_cast<const v2f*>(lattice) + (size_t)l * CAP;

    v2f vA[4], vB[4];
    #pragma unroll
    for (int r = 0; r < 4; ++r) vA[r] = tbl[ixA[r]];
    #pragma unroll
    for (int r = 0; r < 4; ++r) vB[r] = tbl[ixB[r]];

    float oA0 = 0.f, oA1 = 0.f, oB0 = 0.f, oB1 = 0.f;
    #pragma unroll
    for (int r = 0; r < 4; ++r) {
        oA0 += wA[r] * vA[r].x;  oA1 += wA[r] * vA[r].y;
        oB0 += wB[r] * vB[r].x;  oB1 += wB[r] * vB[r].y;
    }

    const uint32_t uA = pack_h2_scaled(oA0 * an, oA1 * an);
    const uint32_t uB = pack_h2_scaled(oB0 * an, oB1 * an);

    uint32_t* pWA = ws_u + (size_t)l * NPOINTS + pbase + t;
    __builtin_nontemporal_store(uA, pWA);
    __builtin_nontemporal_store(uB, pWA + 256);
}

// LDS-free transpose: 4 lanes per point; lane m holds output cols 12m..12m+11.
__global__ __launch_bounds__(256) void transpose_kernel(
    const uint32_t* __restrict__ ws_u,   // [L][N] half2 scaled
    const uint32_t* __restrict__ pos4u,  // pos4 as uints (w = orig index)
    float* __restrict__ out)             // [N][48]
{
    const int t  = threadIdx.x;
    const int m  = t & 3;
    const int p  = blockIdx.x * 64 + (t >> 2);

    const uint32_t orig = pos4u[4*p + 3];

    float r[12];
    #pragma unroll
    for (int i = 0; i < 6; ++i) {
        const int l = m * 6 + i;
        const uint32_t u = ws_u[(size_t)l * NPOINTS + p];
        const f16x2 hh = __builtin_bit_cast(f16x2, u);
        r[2*i+0] = (float)hh.x * 0.00390625f;   // /256 exact
        r[2*i+1] = (float)hh.y * 0.00390625f;
    }

    float* orow = out + (size_t)orig * 48 + m * 12;
    #pragma unroll
    for (int j = 0; j < 3; ++j) {
        v4f v; v.x = r[4*j]; v.y = r[4*j+1]; v.z = r[4*j+2]; v.w = r[4*j+3];
        *reinterpret_cast<v4f*>(orow + 4*j) = v;
    }
}

// Fallback (ws too small): unsorted, direct scattered out writes.
__global__ __launch_bounds__(256) void permuto_direct(
    const float* __restrict__ pos,
    const float* __restrict__ lattice,
    const float* __restrict__ shift,
    const float* __restrict__ anneal,
    const float* __restrict__ scale,
    float* __restrict__ out)
{
    const int tid = blockIdx.x * 256 + threadIdx.x;
    const int n = tid / NLEV;
    const int l = tid - n * NLEV;

    const float sc  = scale[l];
    const float sf0 = sc / sqrtf(2.0f);
    const float sf1 = sc / sqrtf(6.0f);
    const float sf2 = sc / sqrtf(12.0f);

    uint32_t ix[4]; float w[4];
    prep_point(pos[n*3+0], pos[n*3+1], pos[n*3+2],
               sf0, sf1, sf2, shift[l*3+0], shift[l*3+1], shift[l*3+2], ix, w);

    const v2f* tbl = reinterpret_cast<const v2f*>(lattice) + (size_t)l * CAP;
    float o0 = 0.f, o1 = 0.f;
    #pragma unroll
    for (int r = 0; r < 4; ++r) {
        v2f v = tbl[ix[r]];
        o0 += w[r] * v.x;  o1 += w[r] * v.y;
    }
    const float an = anneal[l];
    v2f res; res.x = o0 * an; res.y = o1 * an;
    *reinterpret_cast<v2f*>(out + (size_t)n * (NLEV*2) + l*2) = res;
}

extern "C" void kernel_launch(void* const* d_in, const int* in_sizes, int n_in,
                              void* d_out, int out_size, void* d_ws, size_t ws_size,
                              hipStream_t stream) {
    const float* pos     = (const float*)d_in[0];
    const float* lattice = (const float*)d_in[1];
    const float* shift   = (const float*)d_in[2];
    const float* anneal  = (const float*)d_in[3];
    const float* scale   = (const float*)d_in[4];
    float* out = (float*)d_out;

    uint8_t* w8 = (uint8_t*)d_ws;
    uint32_t* ws_u  = (uint32_t*)w8;
    v4f*      pos4  = (v4f*)(w8 + WS_H_B);
    int*      part  = (int*)(w8 + WS_H_B + POS4_B);
    int*      basep = (int*)(w8 + WS_H_B + POS4_B + PART_B);
    int*      tot   = (int*)(w8 + WS_H_B + POS4_B + PART_B + BASE_B);
    int*      G     = (int*)(w8 + WS_H_B + POS4_B + PART_B + BASE_B + TOT_B);
    const size_t need = WS_H_B + POS4_B + PART_B + BASE_B + 2 * TOT_B;

    if (ws_size >= need) {
        hist_kernel   <<<SORT_BLOCKS, 256, 0, stream>>>(pos, part);
        scanA_kernel  <<<NBUCKET / 256, 256, 0, stream>>>(part, tot);
        scanB_kernel  <<<1, 256, 0, stream>>>(tot, G);
        scanC_kernel  <<<NBUCKET / 256, 256, 0, stream>>>(part, G, basep);
        scatter_kernel<<<SORT_BLOCKS, 256, 0, stream>>>(pos, basep, pos4);
        permuto_kernel<<<NLEV * BLOCKS_PER_LEVEL, 256, 0, stream>>>(
            pos4, lattice, shift, anneal, scale, ws_u);
        transpose_kernel<<<NPOINTS / 64, 256, 0, stream>>>(
            ws_u, (const uint32_t*)pos4, out);
    } else {
        permuto_direct<<<(NPOINTS * NLEV) / 256, 256, 0, stream>>>(
            pos, lattice, shift, anneal, scale, out);
    }
}

// Round 10
// 234.897 us; speedup vs baseline: 1.4882x; 1.0173x over previous
//
#include <hip/hip_runtime.h>
#include <cstdint>

#define NPOINTS 524288
#define NLEV 24
#define CAP 262144
#define HASHMUL 2531011u
#define PTS_PER_BLOCK 512
#define BLOCKS_PER_LEVEL (NPOINTS / PTS_PER_BLOCK)   // 1024

#define NBUCKET 4096              // 4 bits per dim, 12-bit Morton
#define SORT_BLOCKS 64
#define SORT_PTS (NPOINTS / SORT_BLOCKS)             // 8192 points per sort block

#define WS_H_B   ((size_t)NLEV * NPOINTS * 4)        // 50,331,648 (half2 per (l,n))
#define POS4_B   ((size_t)NPOINTS * 16)              //  8,388,608
#define PART_B   ((size_t)SORT_BLOCKS * NBUCKET * 4) //  1,048,576
#define BASE_B   PART_B
#define TOT_B    ((size_t)NBUCKET * 4)               //     16,384

typedef float v2f  __attribute__((ext_vector_type(2)));
typedef float v4f  __attribute__((ext_vector_type(4)));
typedef _Float16 f16x2 __attribute__((ext_vector_type(2)));

// ---------------- sorting (no global atomics) ----------------

__device__ __forceinline__ uint32_t expand_bits(uint32_t v) {
    v = (v | (v << 16)) & 0x030000FFu;
    v = (v | (v << 8))  & 0x0300F00Fu;
    v = (v | (v << 4))  & 0x030C30C3u;
    v = (v | (v << 2))  & 0x09249249u;
    return v;
}

__device__ __forceinline__ uint32_t morton4(float x, float y, float z) {
    int xi = (int)(x * 16.0f); xi = xi < 0 ? 0 : (xi > 15 ? 15 : xi);
    int yi = (int)(y * 16.0f); yi = yi < 0 ? 0 : (yi > 15 ? 15 : yi);
    int zi = (int)(z * 16.0f); zi = zi < 0 ? 0 : (zi > 15 ? 15 : zi);
    return expand_bits((uint32_t)xi) | (expand_bits((uint32_t)yi) << 1)
         | (expand_bits((uint32_t)zi) << 2);
}

// per-block LDS histogram -> part[b][j]  (no global atomics)
__global__ __launch_bounds__(256) void hist_kernel(
    const float* __restrict__ pos, int* __restrict__ part) {
    __shared__ int h[NBUCKET];
    const int t = threadIdx.x, b = blockIdx.x;
    #pragma unroll
    for (int i = t; i < NBUCKET; i += 256) h[i] = 0;
    __syncthreads();
    const int n0 = b * SORT_PTS;
    for (int i = 0; i < SORT_PTS / 256; ++i) {
        const int n = n0 + i * 256 + t;
        atomicAdd(&h[morton4(pos[n*3], pos[n*3+1], pos[n*3+2])], 1);
    }
    __syncthreads();
    #pragma unroll
    for (int i = t; i < NBUCKET; i += 256) part[b * NBUCKET + i] = h[i];
}

// tot[j] = sum_b part[b][j]
__global__ __launch_bounds__(256) void scanA_kernel(
    const int* __restrict__ part, int* __restrict__ tot) {
    const int j = blockIdx.x * 256 + threadIdx.x;
    int s = 0;
    #pragma unroll 8
    for (int b = 0; b < SORT_BLOCKS; ++b) s += part[b * NBUCKET + j];
    tot[j] = s;
}

// single-block exclusive scan of tot[NBUCKET] -> G
__global__ __launch_bounds__(256) void scanB_kernel(
    const int* __restrict__ tot, int* __restrict__ G) {
    __shared__ int sums[256];
    const int t = threadIdx.x;
    const int CH = NBUCKET / 256;   // 16
    int loc[CH];
    int s = 0;
    #pragma unroll
    for (int k = 0; k < CH; ++k) { loc[k] = tot[t * CH + k]; s += loc[k]; }
    sums[t] = s;
    __syncthreads();
    for (int d = 1; d < 256; d <<= 1) {
        int v = (t >= d) ? sums[t - d] : 0;
        __syncthreads();
        sums[t] += v;
        __syncthreads();
    }
    int run = sums[t] - s;
    #pragma unroll
    for (int k = 0; k < CH; ++k) { G[t * CH + k] = run; run += loc[k]; }
}

// base[b][j] = G[j] + sum_{b'<b} part[b'][j]
__global__ __launch_bounds__(256) void scanC_kernel(
    const int* __restrict__ part, const int* __restrict__ G,
    int* __restrict__ base) {
    const int j = blockIdx.x * 256 + threadIdx.x;
    int run = G[j];
    #pragma unroll 8
    for (int b = 0; b < SORT_BLOCKS; ++b) {
        base[b * NBUCKET + j] = run;
        run += part[b * NBUCKET + j];
    }
}

// scatter via LDS counters seeded with per-block bases (no global atomics)
__global__ __launch_bounds__(256) void scatter_kernel(
    const float* __restrict__ pos, const int* __restrict__ base,
    v4f* __restrict__ pos4) {
    __shared__ int cnt[NBUCKET];
    const int t = threadIdx.x, b = blockIdx.x;
    #pragma unroll
    for (int i = t; i < NBUCKET; i += 256) cnt[i] = base[b * NBUCKET + i];
    __syncthreads();
    const int n0 = b * SORT_PTS;
    for (int i = 0; i < SORT_PTS / 256; ++i) {
        const int n = n0 + i * 256 + t;
        const float x = pos[n*3], y = pos[n*3+1], z = pos[n*3+2];
        const int slot = atomicAdd(&cnt[morton4(x, y, z)], 1);
        v4f v; v.x = x; v.y = y; v.z = z; v.w = __uint_as_float((uint32_t)n);
        pos4[slot] = v;
    }
}

// ---------------- permuto core ----------------

__device__ __forceinline__ void prep_point(
    const float p0, const float p1, const float p2,
    const float sf0, const float sf1, const float sf2,
    const float sh0, const float sh1, const float sh2,
    uint32_t* __restrict__ ix, float* __restrict__ w)
{
    const float cf0 = (p0 + sh0) * sf0;
    const float cf1 = (p1 + sh1) * sf1;
    const float cf2 = (p2 + sh2) * sf2;

    const float S2 = cf2;
    const float S1 = cf2 + cf1;
    const float S0 = S1 + cf0;

    float E[4];
    E[0] = S0;
    E[1] = S1 - 1.0f*cf0;
    E[2] = S2 - 2.0f*cf1;
    E[3] = 0.0f - 3.0f*cf2;

    float rem0[4];
    float sumrem = 0.0f;
    #pragma unroll
    for (int i = 0; i < 4; ++i) {
        float v  = E[i] * 0.25f;
        float up = ceilf(v)  * 4.0f;
        float dn = floorf(v) * 4.0f;
        rem0[i] = (up - E[i] < E[i] - dn) ? up : dn;
        sumrem += rem0[i];
    }
    const int sum_val = (int)rintf(sumrem * 0.25f);

    float diff[4];
    #pragma unroll
    for (int i = 0; i < 4; ++i) diff[i] = E[i] - rem0[i];

    int rank[4];
    #pragma unroll
    for (int i = 0; i < 4; ++i) {
        int rk = 0;
        #pragma unroll
        for (int j = 0; j < 4; ++j) {
            if (j > i)      rk += (diff[j] >  diff[i]) ? 1 : 0;
            else if (j < i) rk += (diff[j] >= diff[i]) ? 1 : 0;
        }
        rk += sum_val;
        if (rk < 0)      { rk += 4; rem0[i] += 4.0f; }
        else if (rk > 3) { rk -= 4; rem0[i] -= 4.0f; }
        rank[i] = rk;
    }

    float delta[4];
    #pragma unroll
    for (int i = 0; i < 4; ++i) delta[i] = (E[i] - rem0[i]) * 0.25f;

    float b[5];
    #pragma unroll
    for (int k = 0; k < 5; ++k) {
        float acc = 0.0f;
        #pragma unroll
        for (int i = 0; i < 4; ++i) {
            int ti = 3 - rank[i];
            float m = ((ti == k) ? 1.0f : 0.0f) - ((ti == (k-1)) ? 1.0f : 0.0f);
            acc += delta[i] * m;
        }
        b[k] = acc;
    }
    b[0] += 1.0f + b[4];

    int rem0i[4];
    #pragma unroll
    for (int i = 0; i < 4; ++i) rem0i[i] = (int)rintf(rem0[i]);

    #pragma unroll
    for (int r = 0; r < 4; ++r) {
        uint32_t h = 0u;
        #pragma unroll
        for (int i = 0; i < 3; ++i) {
            int key = rem0i[i] + r - 4 * ((rank[i] > 3 - r) ? 1 : 0);
            h = (h + (uint32_t)key) * HASHMUL;
        }
        ix[r] = h & (uint32_t)(CAP - 1);
        w[r]  = b[r];
    }
}

__device__ __forceinline__ uint32_t pack_h2_scaled(float x, float y) {
    f16x2 ph;
    ph.x = (_Float16)(x * 256.0f);   // *2^8 exact; keeps values in f16 normal range
    ph.y = (_Float16)(y * 256.0f);
    return __builtin_bit_cast(uint32_t, ph);
}

// One block = (one XCD's 3 levels, 512 sorted points), 2 points per thread.
// Block stages its points ONCE and loops over levels {xcd, xcd+8, xcd+16} —
// cuts pos4 staging requests/L2 fills 3x. All blocks of an XCD process
// phases in the same order, so ~one 2MB table is L2-resident at a time.
__global__ __launch_bounds__(256, 6) void permuto_kernel(
    const v4f* __restrict__ pos4,       // [N] {x,y,z,orig} sorted
    const float* __restrict__ lattice,  // [L,C,2]
    const float* __restrict__ shift,    // [L,3]
    const float* __restrict__ anneal,   // [L]
    const float* __restrict__ scale,    // [L]
    uint32_t* __restrict__ ws_u)        // [L][N] half2 (scaled by 256)
{
    __shared__ v4f s_pos[PTS_PER_BLOCK];   // 8 KB

    const int t    = threadIdx.x;
    const int bid  = blockIdx.x;
    const int xcd  = bid & 7;
    const int nb   = bid >> 3;            // 0..1023
    const int pbase = nb * PTS_PER_BLOCK;

    {
        const v4f* src = pos4 + pbase;
        s_pos[t]       = src[t];
        s_pos[t + 256] = src[t + 256];
    }
    __syncthreads();

    const v4f pA = s_pos[t];
    const v4f pB = s_pos[t + 256];

    for (int ph = 0; ph < 3; ++ph) {
        const int l = xcd + 8 * ph;

        const float sc  = scale[l];
        const float sf0 = sc / sqrtf(2.0f);
        const float sf1 = sc / sqrtf(6.0f);
        const float sf2 = sc / sqrtf(12.0f);
        const float sh0 = shift[l*3+0];
        const float sh1 = shift[l*3+1];
        const float sh2 = shift[l*3+2];
        const float an  = anneal[l];

        uint32_t ixA[4], ixB[4];
        float    wA[4],  wB[4];
        prep_point(pA.x, pA.y, pA.z, sf0, sf1, sf2, sh0, sh1, sh2, ixA, wA);
        prep_point(pB.x, pB.y, pB.z, sf0, sf1, sf2, sh0, sh1, sh2, ixB, wB);

        const v2f* __restrict__ tbl =
            reinterpret_cast<const v2f*>(lattice) + (size_t)l * CAP;

        v2f vA[4], vB[4];
        #pragma unroll
        for (int r = 0; r < 4; ++r) vA[r] = tbl[ixA[r]];
        #pragma unroll
        for (int r = 0; r < 4; ++r) vB[r] = tbl[ixB[r]];

        float oA0 = 0.f, oA1 = 0.f, oB0 = 0.f, oB1 = 0.f;
        #pragma unroll
        for (int r = 0; r < 4; ++r) {
            oA0 += wA[r] * vA[r].x;  oA1 += wA[r] * vA[r].y;
            oB0 += wB[r] * vB[r].x;  oB1 += wB[r] * vB[r].y;
        }

        const uint32_t uA = pack_h2_scaled(oA0 * an, oA1 * an);
        const uint32_t uB = pack_h2_scaled(oB0 * an, oB1 * an);

        uint32_t* pWA = ws_u + (size_t)l * NPOINTS + pbase + t;
        __builtin_nontemporal_store(uA, pWA);
        __builtin_nontemporal_store(uB, pWA + 256);
    }
}

// LDS-free transpose: 4 lanes per point; lane m holds output cols 12m..12m+11.
__global__ __launch_bounds__(256) void transpose_kernel(
    const uint32_t* __restrict__ ws_u,   // [L][N] half2 scaled
    const uint32_t* __restrict__ pos4u,  // pos4 as uints (w = orig index)
    float* __restrict__ out)             // [N][48]
{
    const int t  = threadIdx.x;
    const int m  = t & 3;
    const int p  = blockIdx.x * 64 + (t >> 2);

    const uint32_t orig = pos4u[4*p + 3];

    float r[12];
    #pragma unroll
    for (int i = 0; i < 6; ++i) {
        const int l = m * 6 + i;
        const uint32_t u = ws_u[(size_t)l * NPOINTS + p];
        const f16x2 hh = __builtin_bit_cast(f16x2, u);
        r[2*i+0] = (float)hh.x * 0.00390625f;   // /256 exact
        r[2*i+1] = (float)hh.y * 0.00390625f;
    }

    float* orow = out + (size_t)orig * 48 + m * 12;
    #pragma unroll
    for (int j = 0; j < 3; ++j) {
        v4f v; v.x = r[4*j]; v.y = r[4*j+1]; v.z = r[4*j+2]; v.w = r[4*j+3];
        *reinterpret_cast<v4f*>(orow + 4*j) = v;
    }
}

// Fallback (ws too small): unsorted, direct scattered out writes.
__global__ __launch_bounds__(256) void permuto_direct(
    const float* __restrict__ pos,
    const float* __restrict__ lattice,
    const float* __restrict__ shift,
    const float* __restrict__ anneal,
    const float* __restrict__ scale,
    float* __restrict__ out)
{
    const int tid = blockIdx.x * 256 + threadIdx.x;
    const int n = tid / NLEV;
    const int l = tid - n * NLEV;

    const float sc  = scale[l];
    const float sf0 = sc / sqrtf(2.0f);
    const float sf1 = sc / sqrtf(6.0f);
    const float sf2 = sc / sqrtf(12.0f);

    uint32_t ix[4]; float w[4];
    prep_point(pos[n*3+0], pos[n*3+1], pos[n*3+2],
               sf0, sf1, sf2, shift[l*3+0], shift[l*3+1], shift[l*3+2], ix, w);

    const v2f* tbl = reinterpret_cast<const v2f*>(lattice) + (size_t)l * CAP;
    float o0 = 0.f, o1 = 0.f;
    #pragma unroll
    for (int r = 0; r < 4; ++r) {
        v2f v = tbl[ix[r]];
        o0 += w[r] * v.x;  o1 += w[r] * v.y;
    }
    const float an = anneal[l];
    v2f res; res.x = o0 * an; res.y = o1 * an;
    *reinterpret_cast<v2f*>(out + (size_t)n * (NLEV*2) + l*2) = res;
}

extern "C" void kernel_launch(void* const* d_in, const int* in_sizes, int n_in,
                              void* d_out, int out_size, void* d_ws, size_t ws_size,
                              hipStream_t stream) {
    const float* pos     = (const float*)d_in[0];
    const float* lattice = (const float*)d_in[1];
    const float* shift   = (const float*)d_in[2];
    const float* anneal  = (const float*)d_in[3];
    const float* scale   = (const float*)d_in[4];
    float* out = (float*)d_out;

    uint8_t* w8 = (uint8_t*)d_ws;
    uint32_t* ws_u  = (uint32_t*)w8;
    v4f*      pos4  = (v4f*)(w8 + WS_H_B);
    int*      part  = (int*)(w8 + WS_H_B + POS4_B);
    int*      basep = (int*)(w8 + WS_H_B + POS4_B + PART_B);
    int*      tot   = (int*)(w8 + WS_H_B + POS4_B + PART_B + BASE_B);
    int*      G     = (int*)(w8 + WS_H_B + POS4_B + PART_B + BASE_B + TOT_B);
    const size_t need = WS_H_B + POS4_B + PART_B + BASE_B + 2 * TOT_B;

    if (ws_size >= need) {
        hist_kernel   <<<SORT_BLOCKS, 256, 0, stream>>>(pos, part);
        scanA_kernel  <<<NBUCKET / 256, 256, 0, stream>>>(part, tot);
        scanB_kernel  <<<1, 256, 0, stream>>>(tot, G);
        scanC_kernel  <<<NBUCKET / 256, 256, 0, stream>>>(part, G, basep);
        scatter_kernel<<<SORT_BLOCKS, 256, 0, stream>>>(pos, basep, pos4);
        permuto_kernel<<<BLOCKS_PER_LEVEL * 8, 256, 0, stream>>>(
            pos4, lattice, shift, anneal, scale, ws_u);
        transpose_kernel<<<NPOINTS / 64, 256, 0, stream>>>(
            ws_u, (const uint32_t*)pos4, out);
    } else {
        permuto_direct<<<(NPOINTS * NLEV) / 256, 256, 0, stream>>>(
            pos, lattice, shift, anneal, scale, out);
    }
}